// Round 1
// baseline (819.019 us; speedup 1.0000x reference)
//
#include <hip/hip_runtime.h>
#include <math.h>

#define EPSV 1e-12f
#define BALLC (1.0f - 1e-6f)
#define MAXT 15.0f

// ws layout (floats):
// [0..127]    mu
// [128..255]  p  (on_manifold)
// [256..383]  q  (= -mobius_add(p, -mu))
// [384..399]  scalars
// [512.. ]    partials: nblk * 129   (k_var reuses first nblk floats)
#define WS_MU 0
#define WS_P 128
#define WS_Q 256
#define WS_SC 384
#define WS_PART 512
#define S_MM 0
#define S_PP 1
#define S_QQ 2
#define S_MP 3
#define S_MQ 4
#define S_PQ 5
#define S_TFM 6
#define S_LAMP 7
#define S_KS 8

__device__ __forceinline__ float qsum4(float v) {
    v += __shfl_xor(v, 1);
    v += __shfl_xor(v, 2);
    return v;
}

__global__ void k_zero(float* ws) {
    int t = threadIdx.x;
    if (t < 128) ws[WS_MU + t] = 0.f;
    if (t < 16) ws[WS_SC + t] = 0.f;
}

// One Karcher pass: per-block partial sums of logmap(mu, x_i).
// logmap(mu,x) = s*( -A/den * mu + B/den * x ), so we accumulate
// vec[c] = sum_i delta_i * x_i[c]   and   alpha = sum_i alpha_i (coeff of mu).
// With mu = 0 this is exactly log0(x).
__global__ __launch_bounds__(256) void k_acc(const float* __restrict__ x,
                                             const float* __restrict__ ws,
                                             float* __restrict__ part, int N) {
    const float mm = ws[WS_SC + S_MM];
    const float tfm = fmaxf(1.f - mm, EPSV);  // = 2/lam(mu)
    const int lane = threadIdx.x & 63;
    const int wv = threadIdx.x >> 6;
    const int q4 = lane & 3;
    const int gid = blockIdx.x * 64 + (threadIdx.x >> 2);
    const int gstride = gridDim.x * 64;

    const float4* mu4 = (const float4*)(ws + WS_MU);
    float4 mur[8];
#pragma unroll
    for (int k = 0; k < 8; k++) mur[k] = mu4[4 * k + q4];

    float4 acc[8];
#pragma unroll
    for (int k = 0; k < 8; k++) acc[k] = make_float4(0.f, 0.f, 0.f, 0.f);
    float accA = 0.f;

    for (int row = gid; row < N; row += gstride) {
        const float4* xr = (const float4*)(x + (size_t)row * 128);
        float4 xv[8];
#pragma unroll
        for (int k = 0; k < 8; k++) xv[k] = xr[4 * k + q4];
        float dpart = 0.f, npart = 0.f;
#pragma unroll
        for (int k = 0; k < 8; k++) {
            dpart += mur[k].x * xv[k].x + mur[k].y * xv[k].y + mur[k].z * xv[k].z + mur[k].w * xv[k].w;
            npart += xv[k].x * xv[k].x + xv[k].y * xv[k].y + xv[k].z * xv[k].z + xv[k].w * xv[k].w;
        }
        float d = qsum4(dpart);
        float X2 = qsum4(npart);
        // m = mobius_add(-mu, x)
        float A = 1.f - 2.f * d + X2;
        float B = 1.f - mm;
        float den = fmaxf(1.f - 2.f * d + mm * X2, EPSV);
        float iv = 1.f / den;
        float m2 = (A * A * mm - 2.f * A * B * d + B * B * X2) * iv * iv;
        float n = sqrtf(fmaxf(m2, EPSV));
        float s = tfm * atanhf(fminf(n, BALLC)) / n;
        float alpha = s * (-A * iv);
        float delta = s * (B * iv);
        accA += alpha;
#pragma unroll
        for (int k = 0; k < 8; k++) {
            acc[k].x += delta * xv[k].x;
            acc[k].y += delta * xv[k].y;
            acc[k].z += delta * xv[k].z;
            acc[k].w += delta * xv[k].w;
        }
    }

    // column sums: reduce over lanes sharing q4 (xor bits 2..5)
#pragma unroll
    for (int m = 4; m < 64; m <<= 1) {
#pragma unroll
        for (int k = 0; k < 8; k++) {
            acc[k].x += __shfl_xor(acc[k].x, m);
            acc[k].y += __shfl_xor(acc[k].y, m);
            acc[k].z += __shfl_xor(acc[k].z, m);
            acc[k].w += __shfl_xor(acc[k].w, m);
        }
    }
    // alpha: one lane per 4-group (lanes of a group hold identical alpha)
#pragma unroll
    for (int m = 4; m < 64; m <<= 1) accA += __shfl_xor(accA, m);

    __shared__ float lvec[4][128];
    __shared__ float lalpha[4];
    if (lane < 4) {
#pragma unroll
        for (int k = 0; k < 8; k++) {
            int c = 16 * k + 4 * lane;
            lvec[wv][c + 0] = acc[k].x;
            lvec[wv][c + 1] = acc[k].y;
            lvec[wv][c + 2] = acc[k].z;
            lvec[wv][c + 3] = acc[k].w;
        }
    }
    if (lane == 0) lalpha[wv] = accA;
    __syncthreads();
    int t = threadIdx.x;
    if (t < 128) {
        part[(size_t)blockIdx.x * 129 + t] = lvec[0][t] + lvec[1][t] + lvec[2][t] + lvec[3][t];
    }
    if (t == 0) {
        part[(size_t)blockIdx.x * 129 + 128] = lalpha[0] + lalpha[1] + lalpha[2] + lalpha[3];
    }
}

// mu <- expmap(mu, mean_tangent). With mu=0 this equals exp0(mean).
__global__ __launch_bounds__(1024) void k_upd(const float* __restrict__ part,
                                              float* __restrict__ ws, int nblk, float invN) {
    __shared__ float lvec[8][128];
    __shared__ float lalpha[8];
    __shared__ float lred[128];
    int t = threadIdx.x;
    int c = t & 127;
    int sg = t >> 7;
    float sum = 0.f;
    for (int b = sg; b < nblk; b += 8) sum += part[(size_t)b * 129 + c];
    lvec[sg][c] = sum;
    if (t < 8) {
        float a = 0.f;
        for (int b = t; b < nblk; b += 8) a += part[(size_t)b * 129 + 128];
        lalpha[t] = a;
    }
    __syncthreads();
    float mm = ws[WS_SC + S_MM];
    float mu_c = 0.f, v = 0.f;
    if (t < 128) {
        float vs = 0.f;
#pragma unroll
        for (int i = 0; i < 8; i++) vs += lvec[i][c];
        float at = 0.f;
#pragma unroll
        for (int i = 0; i < 8; i++) at += lalpha[i];
        mu_c = ws[WS_MU + c];
        v = (vs + at * mu_c) * invN;
    }
    // tree reduce v^2
    if (t < 128) lred[t] = v * v;
    __syncthreads();
    for (int off = 64; off >= 1; off >>= 1) { if (t < off) lred[t] += lred[t + off]; __syncthreads(); }
    float v2 = lred[0];
    __syncthreads();
    float nv = sqrtf(fmaxf(v2, EPSV));
    float lam = 2.f / fmaxf(1.f - mm, EPSV);
    float arg = fminf(fmaxf(lam * nv * 0.5f, -MAXT), MAXT);
    float tt = tanhf(arg);
    float sec = tt * v / nv;
    if (t < 128) lred[t] = mu_c * sec;
    __syncthreads();
    for (int off = 64; off >= 1; off >>= 1) { if (t < off) lred[t] += lred[t + off]; __syncthreads(); }
    float xy = lred[0];
    __syncthreads();
    if (t < 128) lred[t] = sec * sec;
    __syncthreads();
    for (int off = 64; off >= 1; off >>= 1) { if (t < off) lred[t] += lred[t + off]; __syncthreads(); }
    float s2n = lred[0];
    __syncthreads();
    float A = 1.f + 2.f * xy + s2n;
    float B = 1.f - mm;
    float den = fmaxf(1.f + 2.f * xy + mm * s2n, EPSV);
    float munew = (A * mu_c + B * sec) / den;
    if (t < 128) lred[t] = munew * munew;
    __syncthreads();
    for (int off = 64; off >= 1; off >>= 1) { if (t < off) lred[t] += lred[t + off]; __syncthreads(); }
    if (t < 128) ws[WS_MU + t] = munew;
    if (t == 0) ws[WS_SC + S_MM] = lred[0];
}

// variance partials: sum_i dist(x_i, mu)^2  (one float per block)
__global__ __launch_bounds__(256) void k_var(const float* __restrict__ x,
                                             const float* __restrict__ ws,
                                             float* __restrict__ part, int N) {
    const float mm = ws[WS_SC + S_MM];
    const int lane = threadIdx.x & 63;
    const int wv = threadIdx.x >> 6;
    const int q4 = lane & 3;
    const int gid = blockIdx.x * 64 + (threadIdx.x >> 2);
    const int gstride = gridDim.x * 64;
    const float4* mu4 = (const float4*)(ws + WS_MU);
    float4 mur[8];
#pragma unroll
    for (int k = 0; k < 8; k++) mur[k] = mu4[4 * k + q4];
    float accv = 0.f;
    for (int row = gid; row < N; row += gstride) {
        const float4* xr = (const float4*)(x + (size_t)row * 128);
        float4 xv[8];
#pragma unroll
        for (int k = 0; k < 8; k++) xv[k] = xr[4 * k + q4];
        float dpart = 0.f, npart = 0.f;
#pragma unroll
        for (int k = 0; k < 8; k++) {
            dpart += mur[k].x * xv[k].x + mur[k].y * xv[k].y + mur[k].z * xv[k].z + mur[k].w * xv[k].w;
            npart += xv[k].x * xv[k].x + xv[k].y * xv[k].y + xv[k].z * xv[k].z + xv[k].w * xv[k].w;
        }
        float d = qsum4(dpart);
        float X2 = qsum4(npart);
        float A = 1.f - 2.f * d + X2;
        float B = 1.f - mm;
        float den = fmaxf(1.f - 2.f * d + mm * X2, EPSV);
        float iv = 1.f / den;
        float m2 = (A * A * mm - 2.f * A * B * d + B * B * X2) * iv * iv;
        float n = sqrtf(fmaxf(m2, EPSV));
        float dist = 2.f * atanhf(fminf(n, BALLC));
        accv += dist * dist;
    }
    // one lane per group
#pragma unroll
    for (int m = 4; m < 64; m <<= 1) accv += __shfl_xor(accv, m);
    __shared__ float ls[4];
    if (lane == 0) ls[wv] = accv;
    __syncthreads();
    if (threadIdx.x == 0) part[blockIdx.x] = ls[0] + ls[1] + ls[2] + ls[3];
}

// finalize variance; compute p = exp0(mean_param), q = -mobius_add(p,-mu), Gram scalars.
__global__ __launch_bounds__(128) void k_prep(const float* __restrict__ mean_param,
                                              const float* __restrict__ var_param,
                                              const float* __restrict__ part,
                                              float* __restrict__ ws, int nblk, float invN) {
    __shared__ float lred[128];
    int t = threadIdx.x;
#define TREE(val, outv)                                                         \
    lred[t] = (val);                                                            \
    __syncthreads();                                                            \
    for (int off = 64; off >= 1; off >>= 1) {                                   \
        if (t < off) lred[t] += lred[t + off];                                  \
        __syncthreads();                                                        \
    }                                                                           \
    outv = lred[0];                                                             \
    __syncthreads();

    float vs = 0.f;
    for (int b = t; b < nblk; b += 128) vs += part[b];
    float varsum; TREE(vs, varsum);
    float input_var = varsum * invN;

    float mpv = mean_param[t];
    float mpn2; TREE(mpv * mpv, mpn2);
    float pn = sqrtf(fmaxf(mpn2, EPSV));
    float p_c = tanhf(pn) * mpv / pn;
    float pp; TREE(p_c * p_c, pp);
    float mu_c = ws[WS_MU + t];
    float mm = ws[WS_SC + S_MM];
    float pm; TREE(p_c * mu_c, pm);
    // q = -mobius_add(p, -mu)
    float A = 1.f - 2.f * pm + mm;
    float B = 1.f - pp;
    float den = fmaxf(1.f - 2.f * pm + pp * mm, EPSV);
    float q_c = (B * mu_c - A * p_c) / den;
    float qq; TREE(q_c * q_c, qq);
    float mq; TREE(mu_c * q_c, mq);
    float pq; TREE(p_c * q_c, pq);
    float tfm = fmaxf(1.f - mm, EPSV);
    float tfp = fmaxf(1.f - pp, EPSV);
    float lam_p = 2.f / tfp;
    float svar = sqrtf(var_param[0] / (input_var + 1e-6f));
    float ks = (tfp / tfm) * svar;  // (lam_mu/lam_p) * sqrt(var/(input_var+eps))
    ws[WS_P + t] = p_c;
    ws[WS_Q + t] = q_c;
    if (t == 0) {
        ws[WS_SC + S_PP] = pp;  ws[WS_SC + S_QQ] = qq;  ws[WS_SC + S_MP] = pm;
        ws[WS_SC + S_MQ] = mq;  ws[WS_SC + S_PQ] = pq;  ws[WS_SC + S_TFM] = tfm;
        ws[WS_SC + S_LAMP] = lam_p;  ws[WS_SC + S_KS] = ks;
    }
#undef TREE
}

// final pass: out_i = expmap(p, ks * gyr(p,-mu, logmap(mu,x_i)))
// everything stays in span{mu,p,q,x_i}; propagate (coeffs, basis-dots, norm^2).
__global__ __launch_bounds__(256) void k_out(const float* __restrict__ x,
                                             float* __restrict__ out,
                                             const float* __restrict__ ws, int N) {
    const float mm = ws[WS_SC + S_MM], pp = ws[WS_SC + S_PP], qq = ws[WS_SC + S_QQ];
    const float mp = ws[WS_SC + S_MP], mq = ws[WS_SC + S_MQ], pq = ws[WS_SC + S_PQ];
    const float tfm = ws[WS_SC + S_TFM], lam_p = ws[WS_SC + S_LAMP], ks = ws[WS_SC + S_KS];
    const int lane = threadIdx.x & 63;
    const int q4 = lane & 3;
    const int gid = blockIdx.x * 64 + (threadIdx.x >> 2);
    const int gstride = gridDim.x * 64;
    const float4* mu4 = (const float4*)(ws + WS_MU);
    const float4* p4 = (const float4*)(ws + WS_P);
    const float4* qv4 = (const float4*)(ws + WS_Q);
    float4 mur[8], pr[8], qr[8];
#pragma unroll
    for (int k = 0; k < 8; k++) {
        mur[k] = mu4[4 * k + q4];
        pr[k] = p4[4 * k + q4];
        qr[k] = qv4[4 * k + q4];
    }
    for (int row = gid; row < N; row += gstride) {
        const float4* xr = (const float4*)(x + (size_t)row * 128);
        float4 xv[8];
#pragma unroll
        for (int k = 0; k < 8; k++) xv[k] = xr[4 * k + q4];
        float am = 0.f, ap = 0.f, aq = 0.f, an = 0.f;
#pragma unroll
        for (int k = 0; k < 8; k++) {
            am += mur[k].x * xv[k].x + mur[k].y * xv[k].y + mur[k].z * xv[k].z + mur[k].w * xv[k].w;
            ap += pr[k].x * xv[k].x + pr[k].y * xv[k].y + pr[k].z * xv[k].z + pr[k].w * xv[k].w;
            aq += qr[k].x * xv[k].x + qr[k].y * xv[k].y + qr[k].z * xv[k].z + qr[k].w * xv[k].w;
            an += xv[k].x * xv[k].x + xv[k].y * xv[k].y + xv[k].z * xv[k].z + xv[k].w * xv[k].w;
        }
        float Dm = qsum4(am), Dp = qsum4(ap), Dq = qsum4(aq), X2 = qsum4(an);

        // A: m = mobius_add(-mu, x)
        float A = 1.f - 2.f * Dm + X2;
        float B = 1.f - mm;
        float den = fmaxf(1.f - 2.f * Dm + mm * X2, EPSV);
        float iv = 1.f / den;
        float m_cm = -A * iv, m_cx = B * iv;
        float m_dm = (-A * mm + B * Dm) * iv;
        float m_dp = (-A * mp + B * Dp) * iv;
        float m_dq = (-A * mq + B * Dq) * iv;
        float m_n2 = (A * A * mm - 2.f * A * B * Dm + B * B * X2) * iv * iv;
        // B: t = (2/lam_mu) * atanh(||m||)/||m|| * m
        float n1 = sqrtf(fmaxf(m_n2, EPSV));
        float s1 = tfm * atanhf(fminf(n1, BALLC)) / n1;
        float t_cm = s1 * m_cm, t_cx = s1 * m_cx;
        float t_dm = s1 * m_dm, t_dp = s1 * m_dp, t_dq = s1 * m_dq;
        float t_n2 = s1 * s1 * m_n2;
        // C: w1 = mobius_add(-mu, t)
        float xy = -t_dm, y2 = t_n2;
        A = 1.f + 2.f * xy + y2;
        B = 1.f - mm;
        den = fmaxf(1.f + 2.f * xy + mm * y2, EPSV);
        iv = 1.f / den;
        float w_cm = (-A + B * t_cm) * iv;
        float w_cx = B * t_cx * iv;
        float w_dp = (-A * mp + B * t_dp) * iv;
        float w_dq = (-A * mq + B * t_dq) * iv;
        float w_n2 = (A * A * mm + 2.f * A * B * xy + B * B * y2) * iv * iv;
        // D: w2 = mobius_add(p, w1)
        xy = w_dp; y2 = w_n2;
        A = 1.f + 2.f * xy + y2;
        B = 1.f - pp;
        den = fmaxf(1.f + 2.f * xy + pp * y2, EPSV);
        iv = 1.f / den;
        float w2_cm = B * w_cm * iv;
        float w2_cp = A * iv;
        float w2_cx = B * w_cx * iv;
        float w2_dp = (A * pp + B * w_dp) * iv;
        float w2_dq = (A * pq + B * w_dq) * iv;
        float w2_n2 = (A * A * pp + 2.f * A * B * xy + B * B * y2) * iv * iv;
        // E: w3 = mobius_add(q, w2)
        xy = w2_dq; y2 = w2_n2;
        A = 1.f + 2.f * xy + y2;
        B = 1.f - qq;
        den = fmaxf(1.f + 2.f * xy + qq * y2, EPSV);
        iv = 1.f / den;
        float w3_cm = B * w2_cm * iv;
        float w3_cp = B * w2_cp * iv;
        float w3_cq = A * iv;
        float w3_cx = B * w2_cx * iv;
        float w3_dp = (A * pq + B * w2_dp) * iv;
        float w3_n2 = (A * A * qq + 2.f * A * B * xy + B * B * y2) * iv * iv;
        // F+G: u = ks*w3 ; second = tanh(clip(lam_p*||u||/2)) * u/||u||
        float u_n2 = ks * ks * w3_n2;
        float nu = sqrtf(fmaxf(u_n2, EPSV));
        float arg = fminf(fmaxf(lam_p * nu * 0.5f, -MAXT), MAXT);
        float sf = tanhf(arg) * ks / nu;  // second = sf * w3
        float s_cm = sf * w3_cm, s_cp = sf * w3_cp, s_cq = sf * w3_cq, s_cx = sf * w3_cx;
        float s_dp = sf * w3_dp;
        float s_n2 = sf * sf * w3_n2;
        // H: out = mobius_add(p, second)
        xy = s_dp; y2 = s_n2;
        A = 1.f + 2.f * xy + y2;
        B = 1.f - pp;
        den = fmaxf(1.f + 2.f * xy + pp * y2, EPSV);
        iv = 1.f / den;
        float o_cm = B * s_cm * iv;
        float o_cp = (A + B * s_cp) * iv;
        float o_cq = B * s_cq * iv;
        float o_cx = B * s_cx * iv;

        float4* orow = (float4*)(out + (size_t)row * 128);
#pragma unroll
        for (int k = 0; k < 8; k++) {
            float4 o;
            o.x = o_cm * mur[k].x + o_cp * pr[k].x + o_cq * qr[k].x + o_cx * xv[k].x;
            o.y = o_cm * mur[k].y + o_cp * pr[k].y + o_cq * qr[k].y + o_cx * xv[k].y;
            o.z = o_cm * mur[k].z + o_cp * pr[k].z + o_cq * qr[k].z + o_cx * xv[k].z;
            o.w = o_cm * mur[k].w + o_cp * pr[k].w + o_cq * qr[k].w + o_cx * xv[k].w;
            orow[4 * k + q4] = o;
        }
    }
}

extern "C" void kernel_launch(void* const* d_in, const int* in_sizes, int n_in,
                              void* d_out, int out_size, void* d_ws, size_t ws_size,
                              hipStream_t stream) {
    const float* x = (const float*)d_in[0];
    const float* mp = (const float*)d_in[1];
    const float* vp = (const float*)d_in[2];
    float* out = (float*)d_out;
    float* ws = (float*)d_ws;
    int N = in_sizes[0] / 128;
    int nblk = 512;
    size_t need = (size_t)(WS_PART + nblk * 129) * sizeof(float);
    if (ws_size < need) {
        long avail = ((long)(ws_size / sizeof(float)) - WS_PART) / 129;
        nblk = (avail < 8) ? 8 : (int)avail;
        if (nblk > 512) nblk = 512;
    }
    float invN = 1.f / (float)N;
    float* part = ws + WS_PART;

    hipLaunchKernelGGL(k_zero, dim3(1), dim3(128), 0, stream, ws);
    // iteration 0 (mu=0) is exactly the exp0(mean(log0 x)) init; then 15 Karcher steps
    for (int it = 0; it < 16; ++it) {
        hipLaunchKernelGGL(k_acc, dim3(nblk), dim3(256), 0, stream, x, ws, part, N);
        hipLaunchKernelGGL(k_upd, dim3(1), dim3(1024), 0, stream, part, ws, nblk, invN);
    }
    hipLaunchKernelGGL(k_var, dim3(nblk), dim3(256), 0, stream, x, ws, part, N);
    hipLaunchKernelGGL(k_prep, dim3(1), dim3(128), 0, stream, mp, vp, part, ws, nblk, invN);
    hipLaunchKernelGGL(k_out, dim3(1024), dim3(256), 0, stream, x, out, ws, N);
}